// Round 6
// baseline (337.581 us; speedup 1.0000x reference)
//
#include <hip/hip_runtime.h>
#include <hip/hip_bf16.h>
#include <hip/hip_fp16.h>
#include <math.h>

// Problem constants
#define TOKENS   8192
#define DIM      4096
#define NEXP     256
#define TOPK     8
#define CAND     12

// GEMM tiling
#define MT4      32                // tokens per block (round 6: 64 -> 32)
#define BK3      64                // k per staged chunk
#define KG       (DIM / 32)        // 128 k-fragment-groups in W

typedef _Float16 f16x8 __attribute__((ext_vector_type(8)));
typedef float    f32x4 __attribute__((ext_vector_type(4)));

typedef const __attribute__((address_space(1))) unsigned int* gas_ptr;
typedef       __attribute__((address_space(3))) unsigned int* las_ptr;

// ---------------------------------------------------------------------------
// Kernel 0: W fp32 -> fp16 in MFMA-B-fragment-swizzled order.
// 1 KB tiles, tile = ng*KG + kg covers experts [ng*16,+16) x k [kg*32,+32);
// chunk c = q*16+r holds B[n=ng*16+r][k=kg*32+q*8..+8] = lane c's B-fragment.
// ---------------------------------------------------------------------------
__global__ __launch_bounds__(256)
void convert_w(const float* __restrict__ w, _Float16* __restrict__ whs) {
    const int g = blockIdx.x * 256 + threadIdx.x;   // chunk id, 131072 total
    const int tile = g >> 6, c = g & 63;
    const int q = c >> 4, r = c & 15;
    const int ng = tile / KG, kg = tile % KG;
    const int n = ng * 16 + r, k = kg * 32 + q * 8;
    const float4 a = *(const float4*)(w + (size_t)n * DIM + k);
    const float4 b = *(const float4*)(w + (size_t)n * DIM + k + 4);
    f16x8 h;
    h[0] = (_Float16)a.x; h[1] = (_Float16)a.y;
    h[2] = (_Float16)a.z; h[3] = (_Float16)a.w;
    h[4] = (_Float16)b.x; h[5] = (_Float16)b.y;
    h[6] = (_Float16)b.z; h[7] = (_Float16)b.w;
    *(f16x8*)(whs + (size_t)g * 8) = h;
}

// ---------------------------------------------------------------------------
// Kernel 1: partial logits via fp16 MFMA, K-split over blockIdx.y.
// Round 6: MT4 64->32. Round-5 counters showed gemm at 81.6us with grid 512
// = 2 blocks/CU = 8 waves/CU (25% occupancy) vs a ~25us memory floor.
// Now: 32 tokens x 256 experts/block, grid (256,S) = 1024 blocks -> 4
// blocks/CU (LDS 36 KB, launch_bounds(256,4)), wave-tile 32x64, acc[2][4],
// per-thread A-staging halved (one 8-float chunk).
// ---------------------------------------------------------------------------
__global__ __launch_bounds__(256, 4)
void gemm_v4(const float* __restrict__ x, const _Float16* __restrict__ whs,
             float* __restrict__ logits, int kspan) {
    __shared__ _Float16 As[4 * 512];    //  4 tiles x 1 KB = 4 KB
    __shared__ _Float16 Bs[32 * 512];   // 32 tiles x 1 KB = 32 KB

    const int t = threadIdx.x, w = t >> 6, lane = t & 63;
    const int m0 = blockIdx.x * MT4;
    const int kb = blockIdx.y * kspan;
    float* lp    = logits + (size_t)blockIdx.y * TOKENS * NEXP;

    // A staging: thread t -> row am (0..31), k-chunk ack (8 floats)
    const int am  = t >> 3;
    const int ack = t & 7;
    const int amg = am >> 4, amr = am & 15;
    const int aoff = ((amg * 2 + (ack >> 2)) * 64 + (ack & 3) * 16 + amr) * 8;

    f32x4 acc[2][4];
    #pragma unroll
    for (int i = 0; i < 2; ++i)
        #pragma unroll
        for (int j = 0; j < 4; ++j) acc[i][j] = (f32x4){0.f, 0.f, 0.f, 0.f};

    const float* xrow = x + (size_t)(m0 + am) * DIM + ack * 8;
    float4 xr0 = *(const float4*)(xrow + kb);
    float4 xr1 = *(const float4*)(xrow + kb + 4);

    for (int k0 = kb; k0 < kb + kspan; k0 += BK3) {
        // B DMA: wave w stages tiles ti = w*8 .. w*8+7
        #pragma unroll
        for (int c = 0; c < 8; ++c) {
            const int ti  = w * 8 + c;
            const int ng  = ti >> 1, kgl = ti & 1;
            const _Float16* gp = whs + ((size_t)(ng * KG + (k0 >> 5) + kgl)) * 512
                                     + lane * 8;
            __builtin_amdgcn_global_load_lds((gas_ptr)gp, (las_ptr)&Bs[ti * 512],
                                             16, 0, 0);
        }
        // A cvt + frag-order ds_write (one f16x8 per thread)
        {
            f16x8 h0;
            h0[0] = (_Float16)xr0.x; h0[1] = (_Float16)xr0.y;
            h0[2] = (_Float16)xr0.z; h0[3] = (_Float16)xr0.w;
            h0[4] = (_Float16)xr1.x; h0[5] = (_Float16)xr1.y;
            h0[6] = (_Float16)xr1.z; h0[7] = (_Float16)xr1.w;
            *(f16x8*)&As[aoff] = h0;
        }
        __syncthreads();

        if (k0 + BK3 < kb + kspan) {
            xr0 = *(const float4*)(xrow + k0 + BK3);
            xr1 = *(const float4*)(xrow + k0 + BK3 + 4);
        }

        #pragma unroll
        for (int kk = 0; kk < 2; ++kk) {
            f16x8 af[2], bf[4];
            #pragma unroll
            for (int mt = 0; mt < 2; ++mt)
                af[mt] = *(const f16x8*)&As[((mt * 2 + kk) * 64 + lane) * 8];
            #pragma unroll
            for (int nt = 0; nt < 4; ++nt)
                bf[nt] = *(const f16x8*)&Bs[(((w * 4 + nt) * 2 + kk) * 64 + lane) * 8];
            #pragma unroll
            for (int mt = 0; mt < 2; ++mt)
                #pragma unroll
                for (int nt = 0; nt < 4; ++nt)
                    acc[mt][nt] = __builtin_amdgcn_mfma_f32_16x16x32_f16(
                        af[mt], bf[nt], acc[mt][nt], 0, 0, 0);
        }
        __syncthreads();
    }

    // epilogue: C/D layout col=lane&15, row=(lane>>4)*4+reg
    #pragma unroll
    for (int mt = 0; mt < 2; ++mt) {
        #pragma unroll
        for (int nt = 0; nt < 4; ++nt) {
            #pragma unroll
            for (int r = 0; r < 4; ++r) {
                const int m = m0 + mt * 16 + (lane >> 4) * 4 + r;
                const int n = (w * 4 + nt) * 16 + (lane & 15);
                lp[(size_t)m * NEXP + n] = acc[mt][nt][r];
            }
        }
    }
}

// ---------------------------------------------------------------------------
// Kernel 2: fused topk + fp64 rescore, round 11.
// Round-5 post-mortem: triple-buffer took rescore 106->81us (W 14->18.5
// TB/s) -> latency component was real, BW "ceiling" not yet reached.
// This round: (a) depth-4 W prefetch (9 outstanding loads/wave);
// (b) topk_cand folded in — each wave replays the identical 12-round
// selection from the summed logits planes (bitwise-same candidate order),
// saving one kernel launch + the cand round-trip.
// Structure: 1 block = 1 token, 4 waves, 3 candidates/wave, x row staged
// once to LDS (NT), cross-wave combine in LDS, wave 0 ranks+writes.
// ---------------------------------------------------------------------------
__global__ __launch_bounds__(256)
void rescore(const float* __restrict__ x, const float* __restrict__ w,
             const float* __restrict__ logits, float* __restrict__ out,
             int nsplit) {
    __shared__ float  xs[DIM];          // 16 KB: this token's x row
    __shared__ double stot[CAND];
    __shared__ int    sce[CAND];

    const int t = threadIdx.x, wave = t >> 6, lane = t & 63;
    const int token = blockIdx.x;

    // Stage x row -> LDS, NT (read-once stream).
    // global_load_lds dest is wave-uniform base + lane*16.
    const float* xrow = x + (size_t)token * DIM;
    #pragma unroll
    for (int r = 0; r < 4; ++r) {
        const float* gp = xrow + r * 1024 + wave * 256 + lane * 4;
        __builtin_amdgcn_global_load_lds((gas_ptr)gp,
                                         (las_ptr)&xs[r * 1024 + wave * 256],
                                         16, 0, 2 /* NT */);
    }

    // --- In-wave top-CAND selection (verbatim topk_cand logic; every wave
    // replays it so each wave knows its own 3 candidates, no extra sync). ---
    int ce[3];
    {
        const float* lp = logits + (size_t)token * NEXP;
        float s[4];
        #pragma unroll
        for (int j = 0; j < 4; ++j) s[j] = 0.f;
        for (int p = 0; p < nsplit; ++p) {
            const float* pp = lp + (size_t)p * TOKENS * NEXP;
            #pragma unroll
            for (int j = 0; j < 4; ++j) s[j] += pp[j * 64 + lane];
        }
        #pragma unroll
        for (int r = 0; r < CAND; ++r) {
            float bv = s[0];
            int   be = lane;
            #pragma unroll
            for (int j = 1; j < 4; ++j) {
                if (s[j] > bv) { bv = s[j]; be = j * 64 + lane; }
            }
            #pragma unroll
            for (int off = 32; off > 0; off >>= 1) {
                const float ov = __shfl_xor(bv, off, 64);
                const int   oe = __shfl_xor(be, off, 64);
                if (ov > bv || (ov == bv && oe < be)) { bv = ov; be = oe; }
            }
            if (r >= wave * 3 && r < wave * 3 + 3)
                ce[r - wave * 3] = __builtin_amdgcn_readfirstlane(be);
            if ((be & 63) == lane) s[be >> 6] = -1e30f;
        }
    }

    const f32x4* wp[3];
    #pragma unroll
    for (int j = 0; j < 3; ++j)
        wp[j] = (const f32x4*)(w + (size_t)ce[j] * DIM);

    double acc[3];
    #pragma unroll
    for (int j = 0; j < 3; ++j) acc[j] = 0.0;

    // Depth-4 buffer: loads for iter i issue at iter i-3.
    f32x4 wb[4][3];
    #pragma unroll
    for (int j = 0; j < 3; ++j) wb[0][j] = wp[j][lane];
    #pragma unroll
    for (int j = 0; j < 3; ++j) wb[1][j] = wp[j][64 + lane];
    #pragma unroll
    for (int j = 0; j < 3; ++j) wb[2][j] = wp[j][128 + lane];

    __syncthreads();   // xs ready (syncthreads drains vmcnt before barrier)

    #pragma unroll
    for (int i = 0; i < 16; ++i) {
        const int cur = i & 3, nxt = (i + 3) & 3;   // constants under unroll
        if (i < 13) {
            const int o = lane + (i + 3) * 64;
            #pragma unroll
            for (int j = 0; j < 3; ++j) wb[nxt][j] = wp[j][o];
        }
        const f32x4 xv = *(const f32x4*)&xs[(lane + i * 64) * 4];
        const double dx = (double)xv.x, dy = (double)xv.y;
        const double dz = (double)xv.z, dw = (double)xv.w;
        #pragma unroll
        for (int j = 0; j < 3; ++j) {
            const f32x4 wv = wb[cur][j];
            acc[j] = fma(dw, (double)wv.w,
                     fma(dz, (double)wv.z,
                     fma(dy, (double)wv.y,
                     fma(dx, (double)wv.x, acc[j]))));
        }
    }

    // Lane reduce within wave.
    #pragma unroll
    for (int off = 32; off > 0; off >>= 1) {
        #pragma unroll
        for (int j = 0; j < 3; ++j)
            acc[j] += __shfl_xor(acc[j], off, 64);
    }

    if (lane == 0) {
        #pragma unroll
        for (int j = 0; j < 3; ++j) {
            stot[wave * 3 + j] = acc[j];
            sce[wave * 3 + j]  = ce[j];
        }
    }
    __syncthreads();

    // Wave 0: rank the 12 candidates, sigmoid, normalize, write.
    if (wave == 0) {
        double tt[CAND];
        int    ee[CAND];
        #pragma unroll
        for (int c = 0; c < CAND; ++c) { tt[c] = stot[c]; ee[c] = sce[c]; }

        int rank[CAND];
        #pragma unroll
        for (int c = 0; c < CAND; ++c) {
            int r = 0;
            #pragma unroll
            for (int j = 0; j < CAND; ++j) {
                if (j == c) continue;
                if (tt[j] > tt[c] || (tt[j] == tt[c] && ee[j] < ee[c])) ++r;
            }
            rank[c] = r;
        }

        float sig[CAND];
        float sum = 0.f;
        #pragma unroll
        for (int c = 0; c < CAND; ++c) {
            sig[c] = 1.0f / (1.0f + expf(-(float)tt[c]));
            if (rank[c] < TOPK) sum += sig[c];
        }

        if (lane < TOPK) {
            float g = 0.f; int ei = 0;
            #pragma unroll
            for (int c = 0; c < CAND; ++c)
                if (rank[c] == lane) { g = sig[c]; ei = ee[c]; }
            out[(size_t)token * TOPK + lane] = g / sum;
            out[(size_t)TOKENS * TOPK + (size_t)token * TOPK + lane] = (float)ei;
        }
    }
}

extern "C" void kernel_launch(void* const* d_in, const int* in_sizes, int n_in,
                              void* d_out, int out_size, void* d_ws, size_t ws_size,
                              hipStream_t stream) {
    const float* x = (const float*)d_in[0];   // [8192, 4096]
    const float* w = (const float*)d_in[1];   // [256, 4096]
    float* out     = (float*)d_out;

    const size_t plane = (size_t)TOKENS * NEXP * sizeof(float);   // 8 MB
    const size_t fixed = (size_t)NEXP * DIM * sizeof(_Float16);   // 2 MB whs
    int S = 4;
    if (ws_size < 4 * plane + fixed) S = (ws_size >= 2 * plane + fixed) ? 2 : 1;

    float*     logits = (float*)d_ws;
    _Float16*  whs    = (_Float16*)((char*)d_ws + (size_t)S * plane);

    convert_w<<<512, 256, 0, stream>>>(w, whs);
    dim3 ggrid(TOKENS / MT4, S);
    gemm_v4<<<ggrid, 256, 0, stream>>>(x, whs, logits, DIM / S);
    rescore<<<TOKENS, 256, 0, stream>>>(x, w, logits, out, S);
}

// Round 8
// 308.589 us; speedup vs baseline: 1.0939x; 1.0939x over previous
//
#include <hip/hip_runtime.h>
#include <hip/hip_bf16.h>
#include <hip/hip_fp16.h>
#include <math.h>

// Problem constants
#define TOKENS   8192
#define DIM      4096
#define NEXP     256
#define TOPK     8
#define CAND     12

// GEMM tiling
#define MT4      64                // tokens per block (round 7: back to 64)
#define BK3      64                // k per staged chunk
#define KG       (DIM / 32)        // 128 k-fragment-groups in W

typedef _Float16 f16x8 __attribute__((ext_vector_type(8)));
typedef float    f32x4 __attribute__((ext_vector_type(4)));

typedef const __attribute__((address_space(1))) unsigned int* gas_ptr;
typedef       __attribute__((address_space(3))) unsigned int* las_ptr;

// ---------------------------------------------------------------------------
// Kernel 0: W fp32 -> fp16 in MFMA-B-fragment-swizzled order.
// 1 KB tiles, tile = ng*KG + kg covers experts [ng*16,+16) x k [kg*32,+32);
// chunk c = q*16+r holds B[n=ng*16+r][k=kg*32+q*8..+8] = lane c's B-fragment.
// ---------------------------------------------------------------------------
__global__ __launch_bounds__(256)
void convert_w(const float* __restrict__ w, _Float16* __restrict__ whs) {
    const int g = blockIdx.x * 256 + threadIdx.x;   // chunk id, 131072 total
    const int tile = g >> 6, c = g & 63;
    const int q = c >> 4, r = c & 15;
    const int ng = tile / KG, kg = tile % KG;
    const int n = ng * 16 + r, k = kg * 32 + q * 8;
    const float4 a = *(const float4*)(w + (size_t)n * DIM + k);
    const float4 b = *(const float4*)(w + (size_t)n * DIM + k + 4);
    f16x8 h;
    h[0] = (_Float16)a.x; h[1] = (_Float16)a.y;
    h[2] = (_Float16)a.z; h[3] = (_Float16)a.w;
    h[4] = (_Float16)b.x; h[5] = (_Float16)b.y;
    h[6] = (_Float16)b.z; h[7] = (_Float16)b.w;
    *(f16x8*)(whs + (size_t)g * 8) = h;
}

// ---------------------------------------------------------------------------
// Kernel 1: partial logits via fp16 MFMA, K-split over blockIdx.y.
// Round 7: 2-phase double-buffered K-loop (T3 "minimum 2-phase"). Round-5/6
// data falsified occupancy (2->4 blocks/CU: neutral) and B-traffic (2x B:
// neutral) theories for gemm's 81.6us; remaining suspect is the m97 stall:
// stage -> immediate __syncthreads (vmcnt(0) drain) put the full B-staging
// L2 round-trip on the critical path every K-step. Now: stage step k+1's B
// (global_load_lds) and write its A BEFORE computing step k's 32 MFMA, one
// barrier per step; the end-of-step barrier drains vmcnt AFTER compute has
// covered the latency. LDS 2x(8+32) = 80 KB -> 2 blocks/CU; grid (128,S)
// = 512 blocks = exactly co-resident.
// ---------------------------------------------------------------------------
__global__ __launch_bounds__(256, 2)
void gemm_v4(const float* __restrict__ x, const _Float16* __restrict__ whs,
             float* __restrict__ logits, int kspan) {
    __shared__ _Float16 As[2][8 * 512];     // 2 x 8 KB
    __shared__ _Float16 Bs[2][32 * 512];    // 2 x 32 KB

    const int t = threadIdx.x, w = t >> 6, lane = t & 63;
    const int m0 = blockIdx.x * MT4;
    const int kb = blockIdx.y * kspan;
    const int kend = kb + kspan;
    float* lp    = logits + (size_t)blockIdx.y * TOKENS * NEXP;

    // A staging: thread t -> row am (0..63), k-chunks ack, ack+1 (8 halves ea)
    const int am  = t >> 2;
    const int ack = (t & 3) * 2;
    const int amg = am >> 4, amr = am & 15;
    const int aoff0 = ((amg * 2 + (ack >> 2)) * 64 + (ack & 3) * 16 + amr) * 8;
    const int ack1  = ack + 1;
    const int aoff1 = ((amg * 2 + (ack1 >> 2)) * 64 + (ack1 & 3) * 16 + amr) * 8;

    f32x4 acc[4][4];
    #pragma unroll
    for (int i = 0; i < 4; ++i)
        #pragma unroll
        for (int j = 0; j < 4; ++j) acc[i][j] = (f32x4){0.f, 0.f, 0.f, 0.f};

    const float* xrow = x + (size_t)(m0 + am) * DIM + ack * 8;

    // ---- helpers as lambdas (compile-time inlined) ----
    auto stage_B = [&](int buf, int k0) {
        #pragma unroll
        for (int c = 0; c < 8; ++c) {
            const int ti  = w * 8 + c;
            const int ng  = ti >> 1, kgl = ti & 1;
            const _Float16* gp = whs + ((size_t)(ng * KG + (k0 >> 5) + kgl)) * 512
                                     + lane * 8;
            __builtin_amdgcn_global_load_lds((gas_ptr)gp,
                                             (las_ptr)&Bs[buf][ti * 512],
                                             16, 0, 0);
        }
    };
    auto write_A = [&](int buf, const float4& r0, const float4& r1,
                       const float4& r2, const float4& r3) {
        f16x8 h0, h1;
        h0[0] = (_Float16)r0.x; h0[1] = (_Float16)r0.y;
        h0[2] = (_Float16)r0.z; h0[3] = (_Float16)r0.w;
        h0[4] = (_Float16)r1.x; h0[5] = (_Float16)r1.y;
        h0[6] = (_Float16)r1.z; h0[7] = (_Float16)r1.w;
        h1[0] = (_Float16)r2.x; h1[1] = (_Float16)r2.y;
        h1[2] = (_Float16)r2.z; h1[3] = (_Float16)r2.w;
        h1[4] = (_Float16)r3.x; h1[5] = (_Float16)r3.y;
        h1[6] = (_Float16)r3.z; h1[7] = (_Float16)r3.w;
        *(f16x8*)&As[buf][aoff0] = h0;
        *(f16x8*)&As[buf][aoff1] = h1;
    };

    // ---- prologue: stage step 0 into buf 0; prefetch step-1 x ----
    {
        float4 r0 = *(const float4*)(xrow + kb);
        float4 r1 = *(const float4*)(xrow + kb + 4);
        float4 r2 = *(const float4*)(xrow + kb + 8);
        float4 r3 = *(const float4*)(xrow + kb + 12);
        stage_B(0, kb);
        write_A(0, r0, r1, r2, r3);
    }
    float4 xn0, xn1, xn2, xn3;
    if (kb + BK3 < kend) {
        xn0 = *(const float4*)(xrow + kb + BK3);
        xn1 = *(const float4*)(xrow + kb + BK3 + 4);
        xn2 = *(const float4*)(xrow + kb + BK3 + 8);
        xn3 = *(const float4*)(xrow + kb + BK3 + 12);
    }
    __syncthreads();    // buf0 ready (drains vmcnt + lgkm)

    int cur = 0;
    for (int k0 = kb; k0 < kend; k0 += BK3) {
        const int nxt = cur ^ 1;
        const bool has_next = (k0 + BK3 < kend);

        // issue next step's B staging first (latency hides under compute)
        if (has_next) stage_B(nxt, k0 + BK3);

        // compute current step
        #pragma unroll
        for (int kk = 0; kk < 2; ++kk) {
            f16x8 af[4], bf[4];
            #pragma unroll
            for (int mt = 0; mt < 4; ++mt)
                af[mt] = *(const f16x8*)&As[cur][((mt * 2 + kk) * 64 + lane) * 8];
            #pragma unroll
            for (int nt = 0; nt < 4; ++nt)
                bf[nt] = *(const f16x8*)&Bs[cur][(((w * 4 + nt) * 2 + kk) * 64 + lane) * 8];
            #pragma unroll
            for (int mt = 0; mt < 4; ++mt)
                #pragma unroll
                for (int nt = 0; nt < 4; ++nt)
                    acc[mt][nt] = __builtin_amdgcn_mfma_f32_16x16x32_f16(
                        af[mt], bf[nt], acc[mt][nt], 0, 0, 0);
        }

        // write next step's A (xn loaded one step ago)
        if (has_next) write_A(nxt, xn0, xn1, xn2, xn3);

        __syncthreads();    // nxt buffers ready for next iter

        // prefetch x for step k+2
        if (k0 + 2 * BK3 < kend) {
            xn0 = *(const float4*)(xrow + k0 + 2 * BK3);
            xn1 = *(const float4*)(xrow + k0 + 2 * BK3 + 4);
            xn2 = *(const float4*)(xrow + k0 + 2 * BK3 + 8);
            xn3 = *(const float4*)(xrow + k0 + 2 * BK3 + 12);
        }
        cur = nxt;
    }

    // epilogue: C/D layout col=lane&15, row=(lane>>4)*4+reg
    #pragma unroll
    for (int mt = 0; mt < 4; ++mt) {
        #pragma unroll
        for (int nt = 0; nt < 4; ++nt) {
            #pragma unroll
            for (int r = 0; r < 4; ++r) {
                const int m = m0 + mt * 16 + (lane >> 4) * 4 + r;
                const int n = (w * 4 + nt) * 16 + (lane & 15);
                lp[(size_t)m * NEXP + n] = acc[mt][nt][r];
            }
        }
    }
}

// ---------------------------------------------------------------------------
// Kernel 2: sum K-split planes, per-token top-CAND candidates. One wave/token.
// (Round 7: restored as separate kernel — round-6 fusion replicated this
// VALU-serial selection 4x per token inside rescore, +51us.)
// ---------------------------------------------------------------------------
__global__ __launch_bounds__(256)
void topk_cand(const float* __restrict__ logits, int* __restrict__ cand,
               int nsplit) {
    const int lane  = threadIdx.x & 63;
    const int token = blockIdx.x * 4 + (threadIdx.x >> 6);
    const float* lp = logits + (size_t)token * NEXP;

    float s[4];
    #pragma unroll
    for (int j = 0; j < 4; ++j) s[j] = 0.f;
    for (int p = 0; p < nsplit; ++p) {
        const float* pp = lp + (size_t)p * TOKENS * NEXP;
        #pragma unroll
        for (int j = 0; j < 4; ++j) s[j] += pp[j * 64 + lane];
    }

    int mye = 0;
    #pragma unroll
    for (int r = 0; r < CAND; ++r) {
        float bv = s[0];
        int   be = lane;
        #pragma unroll
        for (int j = 1; j < 4; ++j) {
            if (s[j] > bv) { bv = s[j]; be = j * 64 + lane; }
        }
        #pragma unroll
        for (int off = 32; off > 0; off >>= 1) {
            const float ov = __shfl_xor(bv, off, 64);
            const int   oe = __shfl_xor(be, off, 64);
            if (ov > bv || (ov == bv && oe < be)) { bv = ov; be = oe; }
        }
        if (lane == r) mye = be;
        if ((be & 63) == lane) s[be >> 6] = -1e30f;
    }

    if (lane < CAND) cand[token * CAND + lane] = mye;
}

// ---------------------------------------------------------------------------
// Kernel 3: fp64 rescore, round 12 — round-5 structure + depth-4 W prefetch.
// (Round-5 proven: 81.2us at depth-3; depth-4 kept from round 6 — the only
// rescore delta vs the proven config, low-risk.)
// Structure: 1 block = 1 token, 4 waves, 3 candidates/wave, x row staged
// once to LDS (NT), cross-wave combine in LDS, wave 0 ranks+writes.
// ---------------------------------------------------------------------------
__global__ __launch_bounds__(256)
void rescore(const float* __restrict__ x, const float* __restrict__ w,
             const int* __restrict__ cand, float* __restrict__ out) {
    __shared__ float  xs[DIM];          // 16 KB: this token's x row
    __shared__ double stot[CAND];
    __shared__ int    sce[CAND];

    const int t = threadIdx.x, wave = t >> 6, lane = t & 63;
    const int token = blockIdx.x;

    // Stage x row -> LDS, NT (read-once stream).
    const float* xrow = x + (size_t)token * DIM;
    #pragma unroll
    for (int r = 0; r < 4; ++r) {
        const float* gp = xrow + r * 1024 + wave * 256 + lane * 4;
        __builtin_amdgcn_global_load_lds((gas_ptr)gp,
                                         (las_ptr)&xs[r * 1024 + wave * 256],
                                         16, 0, 2 /* NT */);
    }

    // This wave's 3 candidates (scalarized bases).
    int ce[3];
    const f32x4* wp[3];
    #pragma unroll
    for (int j = 0; j < 3; ++j) {
        ce[j] = __builtin_amdgcn_readfirstlane(cand[token * CAND + wave * 3 + j]);
        wp[j] = (const f32x4*)(w + (size_t)ce[j] * DIM);
    }

    double acc[3];
    #pragma unroll
    for (int j = 0; j < 3; ++j) acc[j] = 0.0;

    // Depth-4 buffer: loads for iter i issue at iter i-3 (9 outstanding).
    f32x4 wb[4][3];
    #pragma unroll
    for (int j = 0; j < 3; ++j) wb[0][j] = wp[j][lane];
    #pragma unroll
    for (int j = 0; j < 3; ++j) wb[1][j] = wp[j][64 + lane];
    #pragma unroll
    for (int j = 0; j < 3; ++j) wb[2][j] = wp[j][128 + lane];

    __syncthreads();   // xs ready (syncthreads drains vmcnt before barrier)

    #pragma unroll
    for (int i = 0; i < 16; ++i) {
        const int cur = i & 3, nxt = (i + 3) & 3;   // constants under unroll
        if (i < 13) {
            const int o = lane + (i + 3) * 64;
            #pragma unroll
            for (int j = 0; j < 3; ++j) wb[nxt][j] = wp[j][o];
        }
        const f32x4 xv = *(const f32x4*)&xs[(lane + i * 64) * 4];
        const double dx = (double)xv.x, dy = (double)xv.y;
        const double dz = (double)xv.z, dw = (double)xv.w;
        #pragma unroll
        for (int j = 0; j < 3; ++j) {
            const f32x4 wv = wb[cur][j];
            acc[j] = fma(dw, (double)wv.w,
                     fma(dz, (double)wv.z,
                     fma(dy, (double)wv.y,
                     fma(dx, (double)wv.x, acc[j]))));
        }
    }

    // Lane reduce within wave.
    #pragma unroll
    for (int off = 32; off > 0; off >>= 1) {
        #pragma unroll
        for (int j = 0; j < 3; ++j)
            acc[j] += __shfl_xor(acc[j], off, 64);
    }

    if (lane == 0) {
        #pragma unroll
        for (int j = 0; j < 3; ++j) {
            stot[wave * 3 + j] = acc[j];
            sce[wave * 3 + j]  = ce[j];
        }
    }
    __syncthreads();

    // Wave 0: rank the 12 candidates, sigmoid, normalize, write.
    if (wave == 0) {
        double tt[CAND];
        int    ee[CAND];
        #pragma unroll
        for (int c = 0; c < CAND; ++c) { tt[c] = stot[c]; ee[c] = sce[c]; }

        int rank[CAND];
        #pragma unroll
        for (int c = 0; c < CAND; ++c) {
            int r = 0;
            #pragma unroll
            for (int j = 0; j < CAND; ++j) {
                if (j == c) continue;
                if (tt[j] > tt[c] || (tt[j] == tt[c] && ee[j] < ee[c])) ++r;
            }
            rank[c] = r;
        }

        float sig[CAND];
        float sum = 0.f;
        #pragma unroll
        for (int c = 0; c < CAND; ++c) {
            sig[c] = 1.0f / (1.0f + expf(-(float)tt[c]));
            if (rank[c] < TOPK) sum += sig[c];
        }

        if (lane < TOPK) {
            float g = 0.f; int ei = 0;
            #pragma unroll
            for (int c = 0; c < CAND; ++c)
                if (rank[c] == lane) { g = sig[c]; ei = ee[c]; }
            out[(size_t)token * TOPK + lane] = g / sum;
            out[(size_t)TOKENS * TOPK + (size_t)token * TOPK + lane] = (float)ei;
        }
    }
}

extern "C" void kernel_launch(void* const* d_in, const int* in_sizes, int n_in,
                              void* d_out, int out_size, void* d_ws, size_t ws_size,
                              hipStream_t stream) {
    const float* x = (const float*)d_in[0];   // [8192, 4096]
    const float* w = (const float*)d_in[1];   // [256, 4096]
    float* out     = (float*)d_out;

    const size_t plane = (size_t)TOKENS * NEXP * sizeof(float);   // 8 MB
    const size_t fixed = (size_t)TOKENS * CAND * sizeof(int)
                       + (size_t)NEXP * DIM * sizeof(_Float16);
    int S = 4;
    if (ws_size < 4 * plane + fixed) S = (ws_size >= 2 * plane + fixed) ? 2 : 1;

    float*     logits = (float*)d_ws;
    int*       candp  = (int*)((char*)d_ws + (size_t)S * plane);
    _Float16*  whs    = (_Float16*)((char*)candp + (size_t)TOKENS * CAND * sizeof(int));

    convert_w<<<512, 256, 0, stream>>>(w, whs);
    dim3 ggrid(TOKENS / MT4, S);
    gemm_v4<<<ggrid, 256, 0, stream>>>(x, whs, logits, DIM / S);
    topk_cand<<<TOKENS / 4, 256, 0, stream>>>(logits, candp, S);
    rescore<<<TOKENS, 256, 0, stream>>>(x, w, candp, out);
}